// Round 4
// baseline (661.313 us; speedup 1.0000x reference)
//
#include <hip/hip_runtime.h>
#include <stdint.h>

#define CIN   64
#define COUT  64
#define HH    112
#define WW    112
#define NEXP  4
#define HW    (HH * WW)

typedef short bf16x8 __attribute__((ext_vector_type(8)));
typedef float f32x16 __attribute__((ext_vector_type(16)));

__device__ inline uint16_t f2bf(float f) {
    uint32_t u = __builtin_bit_cast(uint32_t, f);
    return (uint16_t)((u + 0x7FFFu + ((u >> 16) & 1u)) >> 16);
}

// ---------------------------------------------------------------------------
// Fold gates into per-sample weights (bf16) and biases (f32).
// Weff layout: [n][g=72][co=64][j=8] where g = ((phase*9+khw)*2+kq)*2+par,
// k-global ci = phase*32 + (kq*2+par)*8 + j.  co second-fastest => the MFMA
// A-fragment load (lane&31 = co, 16B/lane) reads 512 contiguous bytes.
// ---------------------------------------------------------------------------
__global__ __launch_bounds__(256)
void fold_wb(const float* __restrict__ W, const float* __restrict__ bias,
             const float* __restrict__ mask,
             uint16_t* __restrict__ Weff, float* __restrict__ Beff, int B) {
    int idx = blockIdx.x * 256 + threadIdx.x;
    if (idx >= B * 72 * 512) return;
    int j   = idx & 7;
    int co  = (idx >> 3) & 63;
    int g   = (idx >> 9) % 72;
    int n   = idx / (512 * 72);
    int par   = g & 1;
    int kq    = (g >> 1) & 1;
    int khw   = (g >> 2) % 9;
    int phase = (g >> 2) / 9;
    int ci = phase * 32 + (kq * 2 + par) * 8 + j;
    float acc = 0.f;
#pragma unroll
    for (int e = 0; e < NEXP; ++e)
        acc = fmaf(mask[n * NEXP + e],
                   W[((size_t)(e * COUT + co) * CIN + ci) * 9 + khw], acc);
    Weff[idx] = f2bf(acc);
    if (g == 0 && j == 0) {
        float ba = 0.f;
#pragma unroll
        for (int e = 0; e < NEXP; ++e)
            ba = fmaf(mask[n * NEXP + e], bias[e * COUT + co], ba);
        Beff[n * COUT + co] = ba;
    }
}

// ---------------------------------------------------------------------------
// Fused conv: stage x (NCHW fp32) -> bf16 LDS tile directly (no Xt pass).
// Block = 256 thr (4 waves), 16x16 pixel tile, all 64 cout.
// LDS per phase: [324 pix][32 ci] bf16 = 20736 B; 2 ci-half phases.
// Swizzle: 16B granule slot s holds ci-octet cg = s ^ ((pix>>1)&3).
// ---------------------------------------------------------------------------
__global__ __launch_bounds__(256, 6)
void conv_fused(const float* __restrict__ x, const uint16_t* __restrict__ Weff,
                const float* __restrict__ Beff, float* __restrict__ out,
                int nwg) {
    __shared__ uint16_t ldsx[324 * 32];   // 20736 B

    // T1 XCD swizzle: give each XCD a contiguous chunk of logical blocks so
    // the 49 blocks of a sample share one L2's copy of its 72KB weights.
    int bid = blockIdx.x;
    if ((nwg & 7) == 0)
        bid = (bid & 7) * (nwg >> 3) + (bid >> 3);

    const int tid  = threadIdx.x;
    const int lane = tid & 63;
    const int wid  = tid >> 6;
    const int tileIdx = bid % 49;
    const int n  = bid / 49;
    const int th = tileIdx / 7, tw = tileIdx % 7;
    const int h0 = th * 16, w0 = tw * 16;

    const int rowb = wid * 4 + ((lane & 31) >> 4); // pixel row (nf=0)
    const int colb = lane & 15;                    // pixel col
    const int par  = lane >> 5;                    // k-octet parity

    const uint16_t* wbase = Weff + (size_t)n * 36864
                          + (size_t)par * 512 + (size_t)(lane & 31) * 8;

    f32x16 acc00 = {}, acc01 = {}, acc10 = {}, acc11 = {};

#pragma unroll
    for (int phase = 0; phase < 2; ++phase) {
        if (phase) __syncthreads();   // phase-0 compute done before overwrite
        // ---- stage ci-half tile: 324 pix x 4 granules, 8 ci each
        for (int u = tid; u < 1296; u += 256) {
            int s   = u & 3;
            int pix = u >> 2;
            int dh = pix / 18, dw = pix - dh * 18;
            int h = h0 + dh - 1, w = w0 + dw - 1;
            int cg = s ^ ((pix >> 1) & 3);
            union { uint16_t e[8]; uint4 v; } pk;
            if ((unsigned)h < (unsigned)HH && (unsigned)w < (unsigned)WW) {
                const float* xp = x + ((size_t)(n * CIN + phase * 32 + cg * 8) * HH + h) * WW + w;
#pragma unroll
                for (int j = 0; j < 8; ++j) pk.e[j] = f2bf(xp[(size_t)j * HW]);
            } else {
                pk.v = (uint4){0, 0, 0, 0};
            }
            *(uint4*)(&ldsx[pix * 32 + s * 8]) = pk.v;
        }
        __syncthreads();

        const uint16_t* wp = wbase + (size_t)phase * (36 * 512);
#pragma unroll 1
        for (int khw = 0; khw < 9; ++khw) {
            const int dh = khw / 3;
            const int dw = khw - dh * 3;
            const int pb0 = (rowb + dh) * 18 + (colb + dw);
            const int pb1 = pb0 + 36;              // nf=1: +2 pixel rows
            const int f0 = (pb0 >> 1) & 3, f1 = (pb1 >> 1) & 3;
            const uint16_t* lp0 = &ldsx[pb0 * 32];
            const uint16_t* lp1 = &ldsx[pb1 * 32];
#pragma unroll
            for (int kq = 0; kq < 2; ++kq) {
                const int cgA = kq * 2 + par;
                bf16x8 b0 = *(const bf16x8*)(lp0 + (((cgA ^ f0)) << 3));
                bf16x8 b1 = *(const bf16x8*)(lp1 + (((cgA ^ f1)) << 3));
                const uint16_t* wk = wp + (size_t)((khw * 2 + kq) * 2) * 512;
                bf16x8 a0 = *(const bf16x8*)(wk);
                bf16x8 a1 = *(const bf16x8*)(wk + 256);   // co+32
                acc00 = __builtin_amdgcn_mfma_f32_32x32x16_bf16(a0, b0, acc00, 0, 0, 0);
                acc01 = __builtin_amdgcn_mfma_f32_32x32x16_bf16(a0, b1, acc01, 0, 0, 0);
                acc10 = __builtin_amdgcn_mfma_f32_32x32x16_bf16(a1, b0, acc10, 0, 0, 0);
                acc11 = __builtin_amdgcn_mfma_f32_32x32x16_bf16(a1, b1, acc11, 0, 0, 0);
            }
        }
    }

    // ---- epilogue: C/D layout col=lane&31 (pixel), row=(r&3)+8*(r>>2)+4*par
    const float* bptr = Beff + n * 64;
    const int row0 = h0 + rowb;
    const int col  = w0 + colb;
#pragma unroll
    for (int r = 0; r < 16; ++r) {
        const int co = (r & 3) + 8 * (r >> 2) + 4 * par;
        const float bia0 = bptr[co];
        const float bia1 = bptr[co + 32];
        size_t o00 = ((size_t)(n * COUT + co) * HH + row0) * WW + col;
        out[o00]          = acc00[r] + bia0;
        out[o00 + 2 * WW] = acc01[r] + bia0;
        size_t o10 = o00 + (size_t)32 * HW;
        out[o10]          = acc10[r] + bia1;
        out[o10 + 2 * WW] = acc11[r] + bia1;
    }
}

// ---------------------------------------------------------------------------
// Fallback (round-1 path): per-sample folded weights, fp32 vector conv.
// ---------------------------------------------------------------------------
#define COB   8
#define PIX_PER_BLK 256
#define NTILE (HW / PIX_PER_BLK)

__global__ void fold_weights(const float* __restrict__ W,
                             const float* __restrict__ mask,
                             float* __restrict__ Weff, int B) {
    int idx = blockIdx.x * blockDim.x + threadIdx.x;
    int total = B * CIN * 9 * COUT;
    if (idx >= total) return;
    int co = idx % COUT;
    int t  = idx / COUT;
    int k  = t % 9;
    t /= 9;
    int ci = t % CIN;
    int n  = t / CIN;
    float acc = 0.f;
#pragma unroll
    for (int e = 0; e < NEXP; ++e)
        acc = fmaf(mask[n * NEXP + e],
                   W[(((size_t)(e * COUT + co) * CIN + ci) * 9) + k], acc);
    Weff[idx] = acc;
}

__global__ __launch_bounds__(PIX_PER_BLK, 4)
void conv_gated(const float* __restrict__ x,
                const float* __restrict__ mask,
                const float* __restrict__ bias,
                const float* __restrict__ Weff,
                float* __restrict__ out) {
    const int tile = blockIdx.x % NTILE;
    const int cob  = (blockIdx.x / NTILE) % (COUT / COB);
    const int n    = blockIdx.x / (NTILE * (COUT / COB));
    const int p = tile * PIX_PER_BLK + threadIdx.x;
    const int h = p / WW;
    const int w = p % WW;
    const int co0 = cob * COB;

    float acc[COB];
#pragma unroll
    for (int j = 0; j < COB; ++j) {
        float a = 0.f;
#pragma unroll
        for (int e = 0; e < NEXP; ++e)
            a = fmaf(mask[n * NEXP + e], bias[e * COUT + co0 + j], a);
        acc[j] = a;
    }

    const float* xb = x + (((size_t)n * CIN) * HH + h) * WW + w;
    const float* wb = Weff + ((size_t)n * CIN) * 9 * COUT + co0;
    const bool rok0 = (h > 0), rok2 = (h < HH - 1);
    const bool cok0 = (w > 0), cok2 = (w < WW - 1);

    for (int ci = 0; ci < CIN; ++ci) {
        const float* xc = xb + (size_t)ci * HW;
        const float* wc = wb + (size_t)ci * 9 * COUT;
#pragma unroll
        for (int kh = 0; kh < 3; ++kh) {
            const bool rok = (kh == 0) ? rok0 : ((kh == 2) ? rok2 : true);
#pragma unroll
            for (int kw = 0; kw < 3; ++kw) {
                const bool cok = (kw == 0) ? cok0 : ((kw == 2) ? cok2 : true);
                float xv = (rok && cok) ? xc[(kh - 1) * WW + (kw - 1)] : 0.f;
                const float4* wk = (const float4*)(wc + (kh * 3 + kw) * COUT);
                float4 wa = wk[0], wb4 = wk[1];
                acc[0] = fmaf(xv, wa.x, acc[0]);
                acc[1] = fmaf(xv, wa.y, acc[1]);
                acc[2] = fmaf(xv, wa.z, acc[2]);
                acc[3] = fmaf(xv, wa.w, acc[3]);
                acc[4] = fmaf(xv, wb4.x, acc[4]);
                acc[5] = fmaf(xv, wb4.y, acc[5]);
                acc[6] = fmaf(xv, wb4.z, acc[6]);
                acc[7] = fmaf(xv, wb4.w, acc[7]);
            }
        }
    }
    float* ob = out + (((size_t)(n * COUT + co0)) * HH + h) * WW + w;
#pragma unroll
    for (int j = 0; j < COB; ++j)
        ob[(size_t)j * HW] = acc[j];
}

// ---------------------------------------------------------------------------
extern "C" void kernel_launch(void* const* d_in, const int* in_sizes, int n_in,
                              void* d_out, int out_size, void* d_ws, size_t ws_size,
                              hipStream_t stream) {
    const float* x    = (const float*)d_in[0];
    const float* mask = (const float*)d_in[1];
    const float* W    = (const float*)d_in[2];
    const float* b    = (const float*)d_in[3];
    float* out = (float*)d_out;

    const int B = in_sizes[0] / (CIN * HW);
    const size_t weffB = (size_t)B * 36864 * 2;
    const size_t beffB = (size_t)B * COUT * 4;
    const size_t need  = weffB + beffB;

    if (ws_size >= need) {
        uint16_t* Weff = (uint16_t*)d_ws;
        float*    Beff = (float*)((char*)d_ws + weffB);
        int foldBlocks = (B * 72 * 512 + 255) / 256;
        fold_wb<<<foldBlocks, 256, 0, stream>>>(W, b, mask, Weff, Beff, B);
        const int nwg = B * 49;
        conv_fused<<<nwg, 256, 0, stream>>>(x, Weff, Beff, out, nwg);
    } else {
        float* Weff = (float*)d_ws;
        const size_t weff_elems = (size_t)B * CIN * 9 * COUT;
        int foldBlocks = (int)((weff_elems + 255) / 256);
        fold_weights<<<foldBlocks, 256, 0, stream>>>(W, mask, Weff, B);
        conv_gated<<<B * (COUT / COB) * NTILE, PIX_PER_BLK, 0, stream>>>(
            x, mask, b, Weff, out);
    }
}

// Round 5
// 75.700 us; speedup vs baseline: 8.7360x; 8.7360x over previous
//
#include <hip/hip_runtime.h>
#include <stdint.h>

#define CIN   64
#define COUT  64
#define HH    112
#define WW    112
#define NEXP  4
#define HW    (HH * WW)

typedef short bf16x8 __attribute__((ext_vector_type(8)));
typedef float f32x16 __attribute__((ext_vector_type(16)));

__device__ inline uint16_t f2bf(float f) {
    uint32_t u = __builtin_bit_cast(uint32_t, f);
    return (uint16_t)((u + 0x7FFFu + ((u >> 16) & 1u)) >> 16);
}

// ---------------------------------------------------------------------------
// Fold gates into per-sample weights (bf16) and biases (f32).
// Weff layout: [n][g=72][co=64][j=8] where g = ((phase*9+khw)*2+kq)*2+par,
// k-global ci = phase*32 + (kq*2+par)*8 + j.  co second-fastest => the MFMA
// A-fragment load (lane&31 = co, 16B/lane) reads 512 contiguous bytes.
// ---------------------------------------------------------------------------
__global__ __launch_bounds__(256)
void fold_wb(const float* __restrict__ W, const float* __restrict__ bias,
             const float* __restrict__ mask,
             uint16_t* __restrict__ Weff, float* __restrict__ Beff, int B) {
    int idx = blockIdx.x * 256 + threadIdx.x;
    if (idx >= B * 72 * 512) return;
    int j   = idx & 7;
    int co  = (idx >> 3) & 63;
    int g   = (idx >> 9) % 72;
    int n   = idx / (512 * 72);
    int par   = g & 1;
    int kq    = (g >> 1) & 1;
    int khw   = (g >> 2) % 9;
    int phase = (g >> 2) / 9;
    int ci = phase * 32 + (kq * 2 + par) * 8 + j;
    float acc = 0.f;
#pragma unroll
    for (int e = 0; e < NEXP; ++e)
        acc = fmaf(mask[n * NEXP + e],
                   W[((size_t)(e * COUT + co) * CIN + ci) * 9 + khw], acc);
    Weff[idx] = f2bf(acc);
    if (g == 0 && j == 0) {
        float ba = 0.f;
#pragma unroll
        for (int e = 0; e < NEXP; ++e)
            ba = fmaf(mask[n * NEXP + e], bias[e * COUT + co], ba);
        Beff[n * COUT + co] = ba;
    }
}

// ---------------------------------------------------------------------------
// Fused conv: stage x (NCHW fp32) -> bf16 LDS tile directly (no Xt pass).
// Block = 256 thr (4 waves), 16x16 pixel tile, all 64 cout.
// LDS per phase: [324 pix][32 ci] bf16 = 20736 B; 2 ci-half phases.
// Swizzle: 16B granule slot s holds ci-octet cg = s ^ ((pix>>1)&3).
// NOTE: launch_bounds min-waves MUST stay <=3: the 4 f32x16 accumulators
// need 64 VGPRs; capping the allocator below ~128 spills them to scratch
// (round-4: VGPR=40, 1.77 GB scratch writes, 7x regression).
// ---------------------------------------------------------------------------
__global__ __launch_bounds__(256, 3)
void conv_fused(const float* __restrict__ x, const uint16_t* __restrict__ Weff,
                const float* __restrict__ Beff, float* __restrict__ out,
                int nwg) {
    __shared__ uint16_t ldsx[324 * 32];   // 20736 B

    // T1 XCD swizzle: give each XCD a contiguous chunk of logical blocks so
    // the 49 blocks of a sample share one L2's copy of its 72KB weights.
    int bid = blockIdx.x;
    if ((nwg & 7) == 0)
        bid = (bid & 7) * (nwg >> 3) + (bid >> 3);

    const int tid  = threadIdx.x;
    const int lane = tid & 63;
    const int wid  = tid >> 6;
    const int tileIdx = bid % 49;
    const int n  = bid / 49;
    const int th = tileIdx / 7, tw = tileIdx % 7;
    const int h0 = th * 16, w0 = tw * 16;

    const int rowb = wid * 4 + ((lane & 31) >> 4); // pixel row (nf=0)
    const int colb = lane & 15;                    // pixel col
    const int par  = lane >> 5;                    // k-octet parity

    const uint16_t* wbase = Weff + (size_t)n * 36864
                          + (size_t)par * 512 + (size_t)(lane & 31) * 8;

    f32x16 acc00 = {}, acc01 = {}, acc10 = {}, acc11 = {};

#pragma unroll
    for (int phase = 0; phase < 2; ++phase) {
        if (phase) __syncthreads();   // phase-0 compute done before overwrite
        // ---- stage ci-half tile: 324 pix x 4 granules, 8 ci each
        for (int u = tid; u < 1296; u += 256) {
            int s   = u & 3;
            int pix = u >> 2;
            int dh = pix / 18, dw = pix - dh * 18;
            int h = h0 + dh - 1, w = w0 + dw - 1;
            int cg = s ^ ((pix >> 1) & 3);
            union { uint16_t e[8]; uint4 v; } pk;
            if ((unsigned)h < (unsigned)HH && (unsigned)w < (unsigned)WW) {
                const float* xp = x + ((size_t)(n * CIN + phase * 32 + cg * 8) * HH + h) * WW + w;
#pragma unroll
                for (int j = 0; j < 8; ++j) pk.e[j] = f2bf(xp[(size_t)j * HW]);
            } else {
                pk.v = (uint4){0, 0, 0, 0};
            }
            *(uint4*)(&ldsx[pix * 32 + s * 8]) = pk.v;
        }
        __syncthreads();

        const uint16_t* wp = wbase + (size_t)phase * (36 * 512);
#pragma unroll 1
        for (int khw = 0; khw < 9; ++khw) {
            const int dh = khw / 3;
            const int dw = khw - dh * 3;
            const int pb0 = (rowb + dh) * 18 + (colb + dw);
            const int pb1 = pb0 + 36;              // nf=1: +2 pixel rows
            const int f0 = (pb0 >> 1) & 3, f1 = (pb1 >> 1) & 3;
            const uint16_t* lp0 = &ldsx[pb0 * 32];
            const uint16_t* lp1 = &ldsx[pb1 * 32];
#pragma unroll
            for (int kq = 0; kq < 2; ++kq) {
                const int cgA = kq * 2 + par;
                bf16x8 b0 = *(const bf16x8*)(lp0 + (((cgA ^ f0)) << 3));
                bf16x8 b1 = *(const bf16x8*)(lp1 + (((cgA ^ f1)) << 3));
                const uint16_t* wk = wp + (size_t)((khw * 2 + kq) * 2) * 512;
                bf16x8 a0 = *(const bf16x8*)(wk);
                bf16x8 a1 = *(const bf16x8*)(wk + 256);   // co+32
                acc00 = __builtin_amdgcn_mfma_f32_32x32x16_bf16(a0, b0, acc00, 0, 0, 0);
                acc01 = __builtin_amdgcn_mfma_f32_32x32x16_bf16(a0, b1, acc01, 0, 0, 0);
                acc10 = __builtin_amdgcn_mfma_f32_32x32x16_bf16(a1, b0, acc10, 0, 0, 0);
                acc11 = __builtin_amdgcn_mfma_f32_32x32x16_bf16(a1, b1, acc11, 0, 0, 0);
            }
        }
    }

    // ---- epilogue: C/D layout col=lane&31 (pixel), row=(r&3)+8*(r>>2)+4*par
    const float* bptr = Beff + n * 64;
    const int row0 = h0 + rowb;
    const int col  = w0 + colb;
#pragma unroll
    for (int r = 0; r < 16; ++r) {
        const int co = (r & 3) + 8 * (r >> 2) + 4 * par;
        const float bia0 = bptr[co];
        const float bia1 = bptr[co + 32];
        size_t o00 = ((size_t)(n * COUT + co) * HH + row0) * WW + col;
        out[o00]          = acc00[r] + bia0;
        out[o00 + 2 * WW] = acc01[r] + bia0;
        size_t o10 = o00 + (size_t)32 * HW;
        out[o10]          = acc10[r] + bia1;
        out[o10 + 2 * WW] = acc11[r] + bia1;
    }
}

// ---------------------------------------------------------------------------
// Fallback (round-1 path): per-sample folded weights, fp32 vector conv.
// ---------------------------------------------------------------------------
#define COB   8
#define PIX_PER_BLK 256
#define NTILE (HW / PIX_PER_BLK)

__global__ void fold_weights(const float* __restrict__ W,
                             const float* __restrict__ mask,
                             float* __restrict__ Weff, int B) {
    int idx = blockIdx.x * blockDim.x + threadIdx.x;
    int total = B * CIN * 9 * COUT;
    if (idx >= total) return;
    int co = idx % COUT;
    int t  = idx / COUT;
    int k  = t % 9;
    t /= 9;
    int ci = t % CIN;
    int n  = t / CIN;
    float acc = 0.f;
#pragma unroll
    for (int e = 0; e < NEXP; ++e)
        acc = fmaf(mask[n * NEXP + e],
                   W[(((size_t)(e * COUT + co) * CIN + ci) * 9) + k], acc);
    Weff[idx] = acc;
}

__global__ __launch_bounds__(PIX_PER_BLK, 4)
void conv_gated(const float* __restrict__ x,
                const float* __restrict__ mask,
                const float* __restrict__ bias,
                const float* __restrict__ Weff,
                float* __restrict__ out) {
    const int tile = blockIdx.x % NTILE;
    const int cob  = (blockIdx.x / NTILE) % (COUT / COB);
    const int n    = blockIdx.x / (NTILE * (COUT / COB));
    const int p = tile * PIX_PER_BLK + threadIdx.x;
    const int h = p / WW;
    const int w = p % WW;
    const int co0 = cob * COB;

    float acc[COB];
#pragma unroll
    for (int j = 0; j < COB; ++j) {
        float a = 0.f;
#pragma unroll
        for (int e = 0; e < NEXP; ++e)
            a = fmaf(mask[n * NEXP + e], bias[e * COUT + co0 + j], a);
        acc[j] = a;
    }

    const float* xb = x + (((size_t)n * CIN) * HH + h) * WW + w;
    const float* wb = Weff + ((size_t)n * CIN) * 9 * COUT + co0;
    const bool rok0 = (h > 0), rok2 = (h < HH - 1);
    const bool cok0 = (w > 0), cok2 = (w < WW - 1);

    for (int ci = 0; ci < CIN; ++ci) {
        const float* xc = xb + (size_t)ci * HW;
        const float* wc = wb + (size_t)ci * 9 * COUT;
#pragma unroll
        for (int kh = 0; kh < 3; ++kh) {
            const bool rok = (kh == 0) ? rok0 : ((kh == 2) ? rok2 : true);
#pragma unroll
            for (int kw = 0; kw < 3; ++kw) {
                const bool cok = (kw == 0) ? cok0 : ((kw == 2) ? cok2 : true);
                float xv = (rok && cok) ? xc[(kh - 1) * WW + (kw - 1)] : 0.f;
                const float4* wk = (const float4*)(wc + (kh * 3 + kw) * COUT);
                float4 wa = wk[0], wb4 = wk[1];
                acc[0] = fmaf(xv, wa.x, acc[0]);
                acc[1] = fmaf(xv, wa.y, acc[1]);
                acc[2] = fmaf(xv, wa.z, acc[2]);
                acc[3] = fmaf(xv, wa.w, acc[3]);
                acc[4] = fmaf(xv, wb4.x, acc[4]);
                acc[5] = fmaf(xv, wb4.y, acc[5]);
                acc[6] = fmaf(xv, wb4.z, acc[6]);
                acc[7] = fmaf(xv, wb4.w, acc[7]);
            }
        }
    }
    float* ob = out + (((size_t)(n * COUT + co0)) * HH + h) * WW + w;
#pragma unroll
    for (int j = 0; j < COB; ++j)
        ob[(size_t)j * HW] = acc[j];
}

// ---------------------------------------------------------------------------
extern "C" void kernel_launch(void* const* d_in, const int* in_sizes, int n_in,
                              void* d_out, int out_size, void* d_ws, size_t ws_size,
                              hipStream_t stream) {
    const float* x    = (const float*)d_in[0];
    const float* mask = (const float*)d_in[1];
    const float* W    = (const float*)d_in[2];
    const float* b    = (const float*)d_in[3];
    float* out = (float*)d_out;

    const int B = in_sizes[0] / (CIN * HW);
    const size_t weffB = (size_t)B * 36864 * 2;
    const size_t beffB = (size_t)B * COUT * 4;
    const size_t need  = weffB + beffB;

    if (ws_size >= need) {
        uint16_t* Weff = (uint16_t*)d_ws;
        float*    Beff = (float*)((char*)d_ws + weffB);
        int foldBlocks = (B * 72 * 512 + 255) / 256;
        fold_wb<<<foldBlocks, 256, 0, stream>>>(W, b, mask, Weff, Beff, B);
        const int nwg = B * 49;
        conv_fused<<<nwg, 256, 0, stream>>>(x, Weff, Beff, out, nwg);
    } else {
        float* Weff = (float*)d_ws;
        const size_t weff_elems = (size_t)B * CIN * 9 * COUT;
        int foldBlocks = (int)((weff_elems + 255) / 256);
        fold_weights<<<foldBlocks, 256, 0, stream>>>(W, mask, Weff, B);
        conv_gated<<<B * (COUT / COB) * NTILE, PIX_PER_BLK, 0, stream>>>(
            x, mask, b, Weff, out);
    }
}